// Round 5
// baseline (563.007 us; speedup 1.0000x reference)
//
#include <hip/hip_runtime.h>

#define BB 32
#define NITER 15
#define EPS2 1e-12f   // (1e-6)^2

#define PIT   132               // u16 pitch for 128-wide k rows (2-way LDS conflicts only)
#define PLANE (128*PIT)         // 16896 u16 per plane

typedef unsigned short u16;
typedef __attribute__((ext_vector_type(8))) short  bf16x8;  // 8 bf16 = 4 VGPR (MFMA A/B frag)
typedef __attribute__((ext_vector_type(4))) float  f32x4;   // MFMA C/D frag
typedef __attribute__((ext_vector_type(8))) u16    u16x8;
typedef __attribute__((ext_vector_type(4))) u16    u16x4;

__device__ __forceinline__ u16 f2bf(float x){            // RNE fp32 -> bf16 bits
  unsigned u = __float_as_uint(x);
  return (u16)((u + 0x7FFFu + ((u>>16)&1u)) >> 16);
}
__device__ __forceinline__ float bf2f(u16 h){ return __uint_as_float(((unsigned)h)<<16); }

// ============ init: v = 1, vT planes = (1,0), flag = 1, ctr = 0 ============
__global__ __launch_bounds__(256) void k_initv(float* __restrict__ v, u16* __restrict__ vTp,
                                               int* __restrict__ flag, unsigned* __restrict__ ctr){
  int gid = blockIdx.x*256 + threadIdx.x;               // grid 512 -> 131072 threads
  #pragma unroll
  for (int i = 0; i < 4; ++i){
    int e = gid*4 + i;
    if (e < BB*16384) v[e] = 1.0f;
  }
  #pragma unroll
  for (int i = 0; i < 8; ++i){
    int e = gid*8 + i;
    if (e < BB*32768) vTp[e] = ((e>>14)&1) ? (u16)0 : (u16)0x3F80;  // hi plane=1.0, lo=0
  }
  if (gid == 0){ *flag = 1; *ctr = 0u; }
}

// ============ prep: split (no transpose)  in[128][512] -> planes [128][512] ============
// t: 0:G1->P1 f0, 1:H1->P1 f1, 2:G2->P2 f0, 3:H2->P2 f1.  grid(32, 32, 4)
__global__ __launch_bounds__(256) void k_prep(const float* __restrict__ G1, const float* __restrict__ H1,
                                              const float* __restrict__ G2, const float* __restrict__ H2,
                                              u16* __restrict__ P1p, u16* __restrict__ P2p){
  const int t = blockIdx.z, b = blockIdx.y;
  const float* src = (t==0?G1: t==1?H1: t==2?G2:H2) + (size_t)b*65536;
  u16* dst = (t<2? P1p : P2p) + ((size_t)((t&1)*BB + b))*2*65536;
  const int e0 = (blockIdx.x*256 + threadIdx.x)*8;
  float4 v0 = *(const float4*)(src + e0);
  float4 v1 = *(const float4*)(src + e0 + 4);
  float xs[8] = {v0.x,v0.y,v0.z,v0.w,v1.x,v1.y,v1.z,v1.w};
  u16x8 h, l;
  #pragma unroll
  for (int i = 0; i < 8; ++i){
    u16 hi = f2bf(xs[i]); h[i] = hi; l[i] = f2bf(xs[i] - bf2f(hi));
  }
  *(u16x8*)(dst + e0) = h;
  *(u16x8*)(dst + 65536 + e0) = l;
}

// ============ prepT: transpose + split  in[128][512] -> planes [512][128] ============
// t: 0:H1->Q1T f0, 1:G1->Q1T f1, 2:H2->Q2T f0, 3:G2->Q2T f1.  grid(16, 4, 128) z=b*4+t
__global__ __launch_bounds__(256) void k_prepT(const float* __restrict__ H1, const float* __restrict__ G1,
                                               const float* __restrict__ H2, const float* __restrict__ G2,
                                               u16* __restrict__ Q1T, u16* __restrict__ Q2T){
  const int t = blockIdx.z & 3, b = blockIdx.z >> 2;
  const float* src = (t==0?H1: t==1?G1: t==2?H2:G2) + (size_t)b*65536;   // [128 n][512 m]
  u16* dst = (t<2? Q1T : Q2T) + ((size_t)((t&1)*BB + b))*2*65536;        // [512 m][128 n]
  const int mt = blockIdx.x*32, nt = blockIdx.y*32;
  __shared__ float ts[32][33];
  const int r = threadIdx.x>>3, c4 = (threadIdx.x&7)*4;
  float4 vv = *(const float4*)(src + (size_t)(nt+r)*512 + mt + c4);
  ts[r][c4+0]=vv.x; ts[r][c4+1]=vv.y; ts[r][c4+2]=vv.z; ts[r][c4+3]=vv.w;
  __syncthreads();
  u16x4 h, l;
  #pragma unroll
  for (int i = 0; i < 4; ++i){
    float x = ts[c4+i][r];                 // = src[nt+c4+i][mt+r]
    u16 hi = f2bf(x); h[i] = hi; l[i] = f2bf(x - bf2f(hi));
  }
  size_t o = (size_t)(mt + r)*128 + nt + c4;
  *(u16x4*)(dst + o) = h;
  *(u16x4*)(dst + 65536 + o) = l;
}

// ============ prep MqI: transpose + split-pack Mq[b][m][q] -> u32 (hi | lo<<16) at [b][q][m] ============
// grid(16,16,32)
__global__ __launch_bounds__(256) void k_prepM(const float* __restrict__ Mq, unsigned* __restrict__ MqI){
  const int b = blockIdx.z;
  const float* src = Mq + (size_t)b*262144;
  unsigned* D = MqI + (size_t)b*262144;
  const int mt = blockIdx.x*32, qt = blockIdx.y*32;
  __shared__ float ts[32][33];
  const int r = threadIdx.x>>3, c4 = (threadIdx.x&7)*4;
  float4 vv = *(const float4*)(src + (size_t)(mt+r)*512 + qt + c4);
  ts[r][c4+0]=vv.x; ts[r][c4+1]=vv.y; ts[r][c4+2]=vv.z; ts[r][c4+3]=vv.w;
  __syncthreads();
  uint4 pk;
  unsigned pks[4];
  #pragma unroll
  for (int i = 0; i < 4; ++i){
    float x = ts[c4+i][r];                 // = Mq[mt+c4+i][qt+r]
    u16 hi = f2bf(x);
    pks[i] = (unsigned)hi | ((unsigned)f2bf(x - bf2f(hi)) << 16);
  }
  pk.x=pks[0]; pk.y=pks[1]; pk.z=pks[2]; pk.w=pks[3];
  *(uint4*)(D + (size_t)(qt + r)*512 + mt + c4) = pk;     // MqI[q][m]
}

// ============ staging helper: 128 rows x 128 u16 (hi+lo planes) -> LDS arena (pitch PIT) ============
__device__ __forceinline__ void stage128(const u16* __restrict__ srcH, const u16* __restrict__ srcL,
                                         int gs, u16* __restrict__ dst, int tid){
  #pragma unroll
  for (int i = 0; i < 8; ++i){
    int c = tid + i*256, row = c>>4, seg = c&15;
    u16x8 vh = *(const u16x8*)(srcH + (size_t)row*gs + seg*8);
    u16x8 vl = *(const u16x8*)(srcL + (size_t)row*gs + seg*8);
    *(u16x8*)&dst[row*PIT + seg*8] = vh;
    *(u16x8*)&dst[PLANE + row*PIT + seg*8] = vl;
  }
}

// ============ fused S1+S2: per (f,b,qblk): z1[n][qblk] = P1 . (Mq ⊙ (Q2T . x1^T))^T ============
// grid(256) 1-D with XCD swizzle; block 256 = 4 waves; LDS 135KB (1 block/CU)
__global__ __launch_bounds__(256,1) void k_fuse(const u16* __restrict__ Q2T,
                                                const u16* __restrict__ x1p,
                                                const u16* __restrict__ P1p,
                                                const unsigned* __restrict__ MqI,
                                                u16* __restrict__ z1p,
                                                const int* __restrict__ flag){
  if (*flag == 0) return;
  const int flat = blockIdx.x;
  const int work = (flat & 7)*32 + (flat >> 3);     // bijective; same fb stays on one XCD
  const int fb = work >> 2, qblk = work & 3;
  const int b = fb & 31;

  const int tid = threadIdx.x;
  const int wid = tid>>6, lane = tid&63;
  const int wr = (wid>>1)*64, wc = (wid&1)*64;
  const int l15 = lane&15, g = lane>>4;

  __shared__ __align__(16) u16 smA[2*PLANE];   // Q2T slice -> yTt planes
  __shared__ __align__(16) u16 smB[2*PLANE];   // x1 slice  -> P1 slice

  const u16* Qh = Q2T + (size_t)fb*2*65536 + (size_t)qblk*16384;   // [128 q][128 p]
  const u16* Ql = Qh + 65536;
  const unsigned* Mqb = MqI + (size_t)b*262144;

  f32x4 zacc[4][4];
  #pragma unroll
  for (int i=0;i<4;++i)
    #pragma unroll
    for (int j=0;j<4;++j) zacc[i][j] = (f32x4){0.f,0.f,0.f,0.f};

  for (int mblk = 0; mblk < 4; ++mblk){
    const u16* Xh = x1p + (size_t)fb*2*65536 + (size_t)mblk*16384; // [128 m][128 p]
    const u16* Xl = Xh + 65536;
    stage128(Qh, Ql, 128, smA, tid);
    stage128(Xh, Xl, 128, smB, tid);
    __syncthreads();

    // ---- phase 2: yacc[q][m] = sum_p Q2T[q][p]*x1[m][p], 3-way split ----
    f32x4 yacc[4][4];
    #pragma unroll
    for (int i=0;i<4;++i)
      #pragma unroll
      for (int j=0;j<4;++j) yacc[i][j] = (f32x4){0.f,0.f,0.f,0.f};
    #pragma unroll
    for (int ks=0; ks<4; ++ks){
      bf16x8 ah[4], al[4];
      #pragma unroll
      for (int i=0;i<4;++i){
        int r = wr + i*16 + l15;
        ah[i] = *(const bf16x8*)&smA[r*PIT + ks*32 + g*8];
        al[i] = *(const bf16x8*)&smA[PLANE + r*PIT + ks*32 + g*8];
      }
      #pragma unroll
      for (int j=0;j<4;++j){
        int cc = wc + j*16 + l15;
        bf16x8 bh = *(const bf16x8*)&smB[cc*PIT + ks*32 + g*8];
        bf16x8 bl = *(const bf16x8*)&smB[PLANE + cc*PIT + ks*32 + g*8];
        #pragma unroll
        for (int i=0;i<4;++i){
          yacc[i][j] = __builtin_amdgcn_mfma_f32_16x16x32_bf16(ah[i], bh, yacc[i][j], 0,0,0);
          yacc[i][j] = __builtin_amdgcn_mfma_f32_16x16x32_bf16(al[i], bh, yacc[i][j], 0,0,0);
          yacc[i][j] = __builtin_amdgcn_mfma_f32_16x16x32_bf16(ah[i], bl, yacc[i][j], 0,0,0);
        }
      }
    }
    __syncthreads();   // smA/smB reads complete

    // ---- phase 3: yTt = Mq ⊙ yacc -> split planes into smA; stage P1 slice into smB ----
    #pragma unroll
    for (int i=0;i<4;++i)
      #pragma unroll
      for (int j=0;j<4;++j)
        #pragma unroll
        for (int r=0;r<4;++r){
          int q = wr + i*16 + g*4 + r;         // local q
          int m = wc + j*16 + l15;             // local m
          unsigned mq = Mqb[(size_t)(qblk*128 + q)*512 + mblk*128 + m];
          float mqf = bf2f((u16)(mq & 0xFFFFu)) + bf2f((u16)(mq >> 16));
          float y = yacc[i][j][r] * mqf;
          u16 hi = f2bf(y);
          smA[q*PIT + m] = hi;
          smA[PLANE + q*PIT + m] = f2bf(y - bf2f(hi));
        }
    {
      const u16* Ph = P1p + (size_t)fb*2*65536 + (size_t)mblk*128;  // [128 n][512 m] cols mblk
      const u16* Pl = Ph + 65536;
      stage128(Ph, Pl, 512, smB, tid);
    }
    __syncthreads();

    // ---- phase 5: zacc[n][q] += sum_m P1[n][m]*yTt[q][m], 3-way split ----
    #pragma unroll
    for (int ks=0; ks<4; ++ks){
      bf16x8 ah[4], al[4];
      #pragma unroll
      for (int i=0;i<4;++i){
        int r = wr + i*16 + l15;
        ah[i] = *(const bf16x8*)&smB[r*PIT + ks*32 + g*8];
        al[i] = *(const bf16x8*)&smB[PLANE + r*PIT + ks*32 + g*8];
      }
      #pragma unroll
      for (int j=0;j<4;++j){
        int cc = wc + j*16 + l15;
        bf16x8 bh = *(const bf16x8*)&smA[cc*PIT + ks*32 + g*8];
        bf16x8 bl = *(const bf16x8*)&smA[PLANE + cc*PIT + ks*32 + g*8];
        #pragma unroll
        for (int i=0;i<4;++i){
          zacc[i][j] = __builtin_amdgcn_mfma_f32_16x16x32_bf16(ah[i], bh, zacc[i][j], 0,0,0);
          zacc[i][j] = __builtin_amdgcn_mfma_f32_16x16x32_bf16(al[i], bh, zacc[i][j], 0,0,0);
          zacc[i][j] = __builtin_amdgcn_mfma_f32_16x16x32_bf16(ah[i], bl, zacc[i][j], 0,0,0);
        }
      }
    }
    __syncthreads();   // before next mblk overwrites arenas
  }

  // ---- epilogue: z1 planes [fb][128 n][512 q] ----
  u16* Ch = z1p + (size_t)fb*2*65536;
  u16* Cl = Ch + 65536;
  #pragma unroll
  for (int i=0;i<4;++i)
    #pragma unroll
    for (int j=0;j<4;++j)
      #pragma unroll
      for (int r=0;r<4;++r){
        int n = wr + i*16 + g*4 + r;
        int q = qblk*128 + wc + j*16 + l15;
        float x = zacc[i][j][r];
        u16 hi = f2bf(x);
        Ch[(size_t)n*512 + q] = hi;
        Cl[(size_t)n*512 + q] = f2bf(x - bf2f(hi));
      }
}

// ============ split-bf16 MFMA GEMM (S0: x1, S3: z2 partials) ============
// S=0: x1[m][p]  = Q1T[m][n]  . vT[p][n]    M=512 N=128 K=128           -> x1 planes
// S=3: z2c[n][p] = z1[n][q0+] . P2[p][q0+]  M=128 N=128 K=128 chunk c   -> f32 partials
template<int S>
__global__ __launch_bounds__(256) void k_gemm(const u16* __restrict__ A,
                                              const u16* __restrict__ B,
                                              u16* __restrict__ Co,
                                              float* __restrict__ Cf,
                                              const int* __restrict__ flag){
  if (*flag == 0) return;
  constexpr int KD = (S==3) ? 512 : 128;

  const int flat = blockIdx.x;
  const int work = (flat & 7)*32 + (flat >> 3);

  int fb, rowBlk = 0, colBlk = 0, kBase = 0;
  if (S==0){ fb = work>>2; rowBlk = (work&3)*128; }
  else     { int b = work>>3, f = (work>>2)&1; fb = f*BB + b; kBase = (work&3)*128; }
  const int b = fb & 31;

  const u16* Ah = A + (size_t)fb*2*65536;
  const u16* Al = Ah + 65536;
  size_t bOff, bPl;
  if (S==0){ bOff = (size_t)b*2*16384;   bPl = 16384; }
  else     { bOff = (size_t)fb*2*65536;  bPl = 65536; }
  const u16* Bh = B + bOff;
  const u16* Bl = Bh + bPl;

  const int tid = threadIdx.x;
  const int wid = tid>>6, lane = tid&63;
  const int wr = (wid>>1)*64, wc = (wid&1)*64;
  const int l15 = lane&15, g = lane>>4;

  __shared__ __align__(16) u16 sm[4][128*40];   // 4 planes, 128 rows x 32 k, pitch 40

  f32x4 acc[4][4];
  #pragma unroll
  for (int i=0;i<4;++i)
    #pragma unroll
    for (int j=0;j<4;++j) acc[i][j] = (f32x4){0.f,0.f,0.f,0.f};

  u16x8 pre[4][2];
  #pragma unroll
  for (int i = 0; i < 2; ++i){
    int ch = tid*2 + i;
    int row = ch >> 2, seg = ch & 3;
    size_t gk = (size_t)(kBase + seg*8);
    size_t ga = (size_t)(rowBlk + row)*KD + gk;
    size_t gb = (size_t)(colBlk + row)*KD + gk;
    pre[0][i] = *(const u16x8*)(Ah + ga);
    pre[1][i] = *(const u16x8*)(Al + ga);
    pre[2][i] = *(const u16x8*)(Bh + gb);
    pre[3][i] = *(const u16x8*)(Bl + gb);
  }

  for (int kt = 0; kt < 128; kt += 32){
    #pragma unroll
    for (int i = 0; i < 2; ++i){
      int ch = tid*2 + i;
      int row = ch >> 2, seg = ch & 3;
      int lo = row*40 + seg*8;
      #pragma unroll
      for (int pl = 0; pl < 4; ++pl) *(u16x8*)&sm[pl][lo] = pre[pl][i];
    }
    __syncthreads();
    if (kt + 32 < 128){
      #pragma unroll
      for (int i = 0; i < 2; ++i){
        int ch = tid*2 + i;
        int row = ch >> 2, seg = ch & 3;
        size_t gk = (size_t)(kBase + kt + 32 + seg*8);
        size_t ga = (size_t)(rowBlk + row)*KD + gk;
        size_t gb = (size_t)(colBlk + row)*KD + gk;
        pre[0][i] = *(const u16x8*)(Ah + ga);
        pre[1][i] = *(const u16x8*)(Al + ga);
        pre[2][i] = *(const u16x8*)(Bh + gb);
        pre[3][i] = *(const u16x8*)(Bl + gb);
      }
    }
    bf16x8 ah[4], al[4];
    #pragma unroll
    for (int i=0;i<4;++i){
      int r = wr + i*16 + l15;
      ah[i] = *(const bf16x8*)&sm[0][r*40 + g*8];
      al[i] = *(const bf16x8*)&sm[1][r*40 + g*8];
    }
    #pragma unroll
    for (int j=0;j<4;++j){
      int cc = wc + j*16 + l15;
      bf16x8 bh = *(const bf16x8*)&sm[2][cc*40 + g*8];
      bf16x8 bl = *(const bf16x8*)&sm[3][cc*40 + g*8];
      #pragma unroll
      for (int i=0;i<4;++i){
        acc[i][j] = __builtin_amdgcn_mfma_f32_16x16x32_bf16(ah[i], bh, acc[i][j], 0,0,0);
        acc[i][j] = __builtin_amdgcn_mfma_f32_16x16x32_bf16(al[i], bh, acc[i][j], 0,0,0);
        acc[i][j] = __builtin_amdgcn_mfma_f32_16x16x32_bf16(ah[i], bl, acc[i][j], 0,0,0);
      }
    }
    __syncthreads();
  }

  if (S==3){
    float* Cb = Cf + ((size_t)fb*4 + (size_t)(kBase>>7))*16384;
    #pragma unroll
    for (int i=0;i<4;++i)
      #pragma unroll
      for (int j=0;j<4;++j)
        #pragma unroll
        for (int r=0;r<4;++r){
          int ro = wr + i*16 + g*4 + r, co = wc + j*16 + l15;
          Cb[ro*128 + co] = acc[i][j][r];
        }
  } else {
    u16* Ch = Co + (size_t)fb*2*65536;
    u16* Cl = Ch + 65536;
    #pragma unroll
    for (int i=0;i<4;++i)
      #pragma unroll
      for (int j=0;j<4;++j)
        #pragma unroll
        for (int r=0;r<4;++r){
          int ro = rowBlk + wr + i*16 + g*4 + r, co = wc + j*16 + l15;
          float x = acc[i][j][r];
          u16 hi = f2bf(x);
          Ch[(size_t)ro*128 + co] = hi;
          Cl[(size_t)ro*128 + co] = f2bf(x - bf2f(hi));
        }
  }
}

// ============ fused: t = 0.5*sum(z2p) + Mp.*v ; nrm ; u ; diff ; v=u ; vT planes ; flag ============
// grid(32), block(1024)
__global__ __launch_bounds__(1024) void k_nf(const float* __restrict__ z2p,
                                             const float* __restrict__ Mp,
                                             float* __restrict__ v,
                                             u16* __restrict__ vTp,
                                             float* __restrict__ diff2,
                                             int* __restrict__ flag,
                                             unsigned* __restrict__ ctr){
  if (*flag == 0) return;
  const int b = blockIdx.x, tid = threadIdx.x;
  const size_t base = (size_t)b*16384;
  __shared__ float sred[1024];
  __shared__ float su[128][129];

  float tv[16], vv[16];
  float n2 = 0.f;
  #pragma unroll
  for (int i = 0; i < 16; ++i){
    int e = tid + i*1024;
    float z = 0.f;
    #pragma unroll
    for (int f = 0; f < 2; ++f)
      #pragma unroll
      for (int cc = 0; cc < 4; ++cc)
        z += z2p[(((size_t)f*BB + b)*4 + cc)*16384 + e];
    vv[i] = v[base + e];
    tv[i] = 0.5f*z + Mp[base + e]*vv[i];
    n2 += tv[i]*tv[i];
  }
  sred[tid] = n2; __syncthreads();
  for (int s = 512; s > 0; s >>= 1){ if (tid < s) sred[tid] += sred[tid+s]; __syncthreads(); }
  float nrm2 = sred[0];
  __syncthreads();

  float rn = (nrm2 == 0.f) ? 0.f : 1.0f / sqrtf(nrm2);
  float d2 = 0.f;
  #pragma unroll
  for (int i = 0; i < 16; ++i){
    int e = tid + i*1024;
    float u = tv[i] * rn;
    float d = u - vv[i];
    d2 += d*d;
    v[base + e] = u;
    su[e>>7][e&127] = u;
  }
  sred[tid] = d2; __syncthreads();
  for (int s = 512; s > 0; s >>= 1){ if (tid < s) sred[tid] += sred[tid+s]; __syncthreads(); }

  u16* Ch = vTp + (size_t)b*32768;
  u16* Cl = Ch + 16384;
  #pragma unroll
  for (int i = 0; i < 16; ++i){
    int e = tid + i*1024;                  // e = p*128 + n
    float x = su[e & 127][e >> 7];
    u16 hi = f2bf(x);
    Ch[e] = hi;
    Cl[e] = f2bf(x - bf2f(hi));
  }

  if (tid == 0){
    diff2[b] = sred[0];
    __threadfence();
    unsigned old = atomicAdd(ctr, 1u);
    if (old == (unsigned)(BB - 1)){
      __threadfence();
      int any = 0;
      #pragma unroll
      for (int j = 0; j < BB; ++j) any |= (diff2[j] >= EPS2) ? 1 : 0;
      if (!any) *flag = 0;
      *ctr = 0u;
    }
  }
}

extern "C" void kernel_launch(void* const* d_in, const int* in_sizes, int n_in,
                              void* d_out, int out_size, void* d_ws, size_t ws_size,
                              hipStream_t stream) {
  const float* Mp = (const float*)d_in[0];
  const float* Mq = (const float*)d_in[1];
  const float* G1 = (const float*)d_in[2];
  const float* G2 = (const float*)d_in[3];
  const float* H1 = (const float*)d_in[4];
  const float* H2 = (const float*)d_in[5];
  float* v = (float*)d_out;

  u16* Q1T = (u16*)d_ws;                   //  [2][32][2][512][128]
  u16* Q2T = Q1T + 8388608;                //  [2][32][2][512][128]
  u16* P1p = Q2T + 8388608;                //  [2][32][2][128][512]
  u16* P2p = P1p + 8388608;                //  [2][32][2][128][512]
  u16* x1p = P2p + 8388608;                //  [2][32][2][512][128]
  u16* z1p = x1p + 8388608;                //  [2][32][2][128][512]
  u16* vTp = z1p + 8388608;                //  [32][2][128][128]
  unsigned* MqI = (unsigned*)(vTp + 1048576); // [32][512][512] u32 (hi|lo<<16)
  float* z2p  = (float*)(MqI + 8388608);   //  [2][32][4][128][128]
  float* diff2 = z2p + 4194304;            //  [32]
  int* flag = (int*)(diff2 + 32);
  unsigned* ctr = (unsigned*)(flag + 1);

  k_initv<<<dim3(512), 256, 0, stream>>>(v, vTp, flag, ctr);
  k_prep <<<dim3(32, 32, 4),  256, 0, stream>>>(G1, H1, G2, H2, P1p, P2p);
  k_prepT<<<dim3(16, 4, 128), 256, 0, stream>>>(H1, G1, H2, G2, Q1T, Q2T);
  k_prepM<<<dim3(16, 16, 32), 256, 0, stream>>>(Mq, MqI);

  for (int it = 0; it < NITER; ++it) {
    k_gemm<0><<<dim3(256), 256, 0, stream>>>(Q1T, vTp, x1p, nullptr, flag);
    k_fuse<<<dim3(256), 256, 0, stream>>>(Q2T, x1p, P1p, MqI, z1p, flag);
    k_gemm<3><<<dim3(256), 256, 0, stream>>>(z1p, P2p, nullptr, z2p, flag);
    k_nf<<<dim3(32), 1024, 0, stream>>>(z2p, Mp, v, vTp, diff2, flag, ctr);
  }
}